// Round 6
// baseline (249.537 us; speedup 1.0000x reference)
//
#include <hip/hip_runtime.h>
#include <math.h>

// Kabsch RMSD, fused, LPT work-stealing.
//
// K0 (schedule): one 1024-thread block. Buckets the 4096 rows by
// nIter = ceil(n/256) (1..8), LDS histogram + descending prefix, scatters
// row ids into order[] so the heaviest rows are dispensed first (LPT).
// Zeroes the work-queue counter.
//
// K1 (moments+eig): persistent, 512 blocks x 256 = 2048 waves (8/CU).
// Each wave loops: idx = atomicAdd(next,1); row = order[idx]. Lane l owns
// floats [l*12, l*12+12) of each 768-float segment = 4 whole atoms
// (cross-products thread-local). Only nIter segments are read -> ~44% of
// bytes skipped on average. Software-pipelined segment prefetch. Wave
// shuffle-reduce of 17 f32 moments; lane 0 runs the f64 closed-form 3x3
// eigensolve (C^T C) and writes rmsd directly. No moments buffer, no K2.

#define NACC 17
#define ROWF 6144   // floats per row per array

__global__ __launch_bounds__(1024) void kabsch_schedule_kernel(
    const int* __restrict__ L,
    int* __restrict__ order,    // B ints
    int* __restrict__ next,     // 1 int
    int B)
{
    __shared__ int cnt[8];
    __shared__ int cur[8];
    const int tid = threadIdx.x;

    if (tid < 8) cnt[tid] = 0;
    __syncthreads();

    for (int row = tid; row < B; row += 1024) {
        const int n = L[row] + 1;
        const int b = ((n + 255) >> 8) - 1;      // 0..7
        atomicAdd(&cnt[b], 1);
    }
    __syncthreads();

    if (tid == 0) {
        int acc = 0;
        for (int b = 7; b >= 0; --b) {           // descending nIter
            cur[b] = acc;
            acc += cnt[b];
        }
        *next = 0;
    }
    __syncthreads();

    for (int row = tid; row < B; row += 1024) {
        const int n = L[row] + 1;
        const int b = ((n + 255) >> 8) - 1;
        const int pos = atomicAdd(&cur[b], 1);
        order[pos] = row;
    }
}

__global__ __launch_bounds__(256) void kabsch_rmsd_kernel(
    const float* __restrict__ X,   // B x 6144 f32
    const float* __restrict__ Y,   // B x 6144 f32
    const int* __restrict__ L,     // B
    const int* __restrict__ order, // B (LPT order)
    int* __restrict__ next,        // work-queue counter
    float* __restrict__ OUT,       // B f32
    int B)
{
    const int lane = threadIdx.x & 63;

    for (;;) {
        int idx = 0;
        if (lane == 0) idx = atomicAdd(next, 1);
        idx = __shfl(idx, 0);
        if (idx >= B) return;
        const int row = order[idx];
        const int n = L[row] + 1;              // valid atoms, 2..2047
        const int nIter = (n + 255) >> 8;      // 1..8

        const float* gX = X + (size_t)row * ROWF + (size_t)lane * 12;
        const float* gY = Y + (size_t)row * ROWF + (size_t)lane * 12;

        float v[NACC];
#pragma unroll
        for (int k = 0; k < NACC; ++k) v[k] = 0.0f;

        // prologue: segment 0 (three float4 per array, 48 B lane stride)
        float4 cx0, cx1, cx2, cy0, cy1, cy2;
        {
            const float4* px = (const float4*)gX;
            const float4* py = (const float4*)gY;
            cx0 = px[0]; cx1 = px[1]; cx2 = px[2];
            cy0 = py[0]; cy1 = py[1]; cy2 = py[2];
        }

        for (int it = 0; it < nIter; ++it) {
            float4 nx0, nx1, nx2, ny0, ny1, ny2;
            const bool more = (it + 1 < nIter);
            if (more) {
                const float4* px = (const float4*)(gX + (it + 1) * 768);
                const float4* py = (const float4*)(gY + (it + 1) * 768);
                nx0 = px[0]; nx1 = px[1]; nx2 = px[2];
                ny0 = py[0]; ny1 = py[1]; ny2 = py[2];
            }

            float fx[12], fy[12];
            fx[0]=cx0.x; fx[1]=cx0.y; fx[2]=cx0.z; fx[3]=cx0.w;
            fx[4]=cx1.x; fx[5]=cx1.y; fx[6]=cx1.z; fx[7]=cx1.w;
            fx[8]=cx2.x; fx[9]=cx2.y; fx[10]=cx2.z; fx[11]=cx2.w;
            fy[0]=cy0.x; fy[1]=cy0.y; fy[2]=cy0.z; fy[3]=cy0.w;
            fy[4]=cy1.x; fy[5]=cy1.y; fy[6]=cy1.z; fy[7]=cy1.w;
            fy[8]=cy2.x; fy[9]=cy2.y; fy[10]=cy2.z; fy[11]=cy2.w;

            const int abase = it * 256 + lane * 4;
#pragma unroll
            for (int j = 0; j < 4; ++j) {
                const float msk = (abase + j < n) ? 1.0f : 0.0f;
                const float x0 = fx[3 * j + 0] * msk;
                const float x1 = fx[3 * j + 1] * msk;
                const float x2 = fx[3 * j + 2] * msk;
                const float y0 = fy[3 * j + 0] * msk;
                const float y1 = fy[3 * j + 1] * msk;
                const float y2 = fy[3 * j + 2] * msk;
                v[0] += x0; v[1] += x1; v[2] += x2;
                v[3] += y0; v[4] += y1; v[5] += y2;
                v[6] += x0 * x0 + x1 * x1 + x2 * x2;
                v[7] += y0 * y0 + y1 * y1 + y2 * y2;
                v[8]  += x0 * y0; v[9]  += x0 * y1; v[10] += x0 * y2;
                v[11] += x1 * y0; v[12] += x1 * y1; v[13] += x1 * y2;
                v[14] += x2 * y0; v[15] += x2 * y1; v[16] += x2 * y2;
            }

            if (more) {
                cx0 = nx0; cx1 = nx1; cx2 = nx2;
                cy0 = ny0; cy1 = ny1; cy2 = ny2;
            }
        }

        // wave-64 reduction (no LDS, no barrier)
#pragma unroll
        for (int k = 0; k < NACC; ++k) {
            float t = v[k];
            t += __shfl_down(t, 32);
            t += __shfl_down(t, 16);
            t += __shfl_down(t, 8);
            t += __shfl_down(t, 4);
            t += __shfl_down(t, 2);
            t += __shfl_down(t, 1);
            v[k] = t;
        }

        if (lane == 0) {
            const double inv_n = 1.0 / (double)n;
            const double sx0 = v[0], sx1 = v[1], sx2 = v[2];
            const double sy0 = v[3], sy1 = v[4], sy2 = v[5];
            const double ssq = (double)v[6] + (double)v[7]
                - (sx0 * sx0 + sx1 * sx1 + sx2 * sx2) * inv_n
                - (sy0 * sy0 + sy1 * sy1 + sy2 * sy2) * inv_n;

            double C[3][3];
            C[0][0] = v[8]  - sx0 * sy0 * inv_n;
            C[0][1] = v[9]  - sx0 * sy1 * inv_n;
            C[0][2] = v[10] - sx0 * sy2 * inv_n;
            C[1][0] = v[11] - sx1 * sy0 * inv_n;
            C[1][1] = v[12] - sx1 * sy1 * inv_n;
            C[1][2] = v[13] - sx1 * sy2 * inv_n;
            C[2][0] = v[14] - sx2 * sy0 * inv_n;
            C[2][1] = v[15] - sx2 * sy1 * inv_n;
            C[2][2] = v[16] - sx2 * sy2 * inv_n;

            const double det =
                  C[0][0] * (C[1][1] * C[2][2] - C[1][2] * C[2][1])
                - C[0][1] * (C[1][0] * C[2][2] - C[1][2] * C[2][0])
                + C[0][2] * (C[1][0] * C[2][1] - C[1][1] * C[2][0]);

            double A[3][3];
#pragma unroll
            for (int i = 0; i < 3; ++i)
#pragma unroll
                for (int j = 0; j < 3; ++j)
                    A[i][j] = C[0][i] * C[0][j] + C[1][i] * C[1][j] + C[2][i] * C[2][j];

            const double q  = (A[0][0] + A[1][1] + A[2][2]) / 3.0;
            const double p1 = A[0][1] * A[0][1] + A[0][2] * A[0][2] + A[1][2] * A[1][2];
            const double a00 = A[0][0] - q, a11 = A[1][1] - q, a22 = A[2][2] - q;
            const double p2 = a00 * a00 + a11 * a11 + a22 * a22 + 2.0 * p1;
            const double p  = sqrt(p2 / 6.0);

            double e1, e2, e3;
            if (p < 1e-30) {
                e1 = e2 = e3 = q;
            } else {
                const double ip = 1.0 / p;
                const double b00 = a00 * ip, b11 = a11 * ip, b22 = a22 * ip;
                const double b01 = A[0][1] * ip, b02 = A[0][2] * ip, b12 = A[1][2] * ip;
                double r = 0.5 * (b00 * (b11 * b22 - b12 * b12)
                                - b01 * (b01 * b22 - b12 * b02)
                                + b02 * (b01 * b12 - b11 * b02));
                r = fmin(1.0, fmax(-1.0, r));
                const double phi = acos(r) / 3.0;
                e1 = q + 2.0 * p * cos(phi);
                e3 = q + 2.0 * p * cos(phi + 2.0 * M_PI / 3.0);
                e2 = 3.0 * q - e1 - e3;
            }

            const double S0 = sqrt(fmax(e1, 0.0));
            const double S1 = sqrt(fmax(e2, 0.0));
            const double S2 = sqrt(fmax(e3, 0.0));
            const double d  = (det > 0.0) ? 1.0 : ((det < 0.0) ? -1.0 : 0.0);
            const double tr = S0 + S1 + d * S2;

            const double msd = fmax(ssq - 2.0 * tr, 0.0) * inv_n;
            OUT[row] = (float)sqrt(msd + 1e-12);
        }
    }
}

extern "C" void kernel_launch(void* const* d_in, const int* in_sizes, int n_in,
                              void* d_out, int out_size, void* d_ws, size_t ws_size,
                              hipStream_t stream) {
    const float* X = (const float*)d_in[0];
    const float* Y = (const float*)d_in[1];
    const int* L = (const int*)d_in[2];
    float* OUT = (float*)d_out;

    const int B = in_sizes[2];             // 4096
    int* next  = (int*)d_ws;               // [0]: queue counter
    int* order = (int*)d_ws + 16;          // B ints, 64 B offset

    kabsch_schedule_kernel<<<1, 1024, 0, stream>>>(L, order, next, B);
    kabsch_rmsd_kernel<<<512, 256, 0, stream>>>(X, Y, L, order, next, OUT, B);
}

// Round 7
// 234.857 us; speedup vs baseline: 1.0625x; 1.0625x over previous
//
#include <hip/hip_runtime.h>
#include <math.h>

// Kabsch RMSD, two kernels, static 2-wave-per-row split.
//
// K1 (moments): 2048 blocks x 256 threads = 8192 waves; waves {2r, 2r+1}
// handle row r's even/odd 256-atom segments (validity-skipped: only
// nIter = ceil(n/256) segments exist). Lane l owns floats [l*12, l*12+12)
// of its segment = 4 whole atoms (all cross-products thread-local).
// Prefetch-1 software pipeline. Wave shuffle-reduce of 17 f32 moments,
// then a single LDS combine of the wave pair -> WS[k*B + row].
// Rationale (R2-R6 evidence): kernel is latency/MLP-bound, not BW-bound --
// doubling resident waves and halving per-wave max work attacks exactly
// that. No atomics, no work queue (R6's queue serialized and cost 2x).
//
// K2 (eigensolve): one lane per row, f64 closed-form 3x3 symmetric
// eigensolver on C^T C -> singular values -> rmsd.

#define NACC 17
#define ROWF 6144   // floats per row per array

__global__ __launch_bounds__(256, 6) void kabsch_moments_kernel(
    const float* __restrict__ X,   // B x 6144 f32
    const float* __restrict__ Y,   // B x 6144 f32
    const int* __restrict__ L,     // B
    float* __restrict__ WS,        // NACC x B (transposed)
    int B)
{
    const int tid  = threadIdx.x;
    const int lane = tid & 63;
    const int w    = tid >> 6;            // wave in block, 0..3
    const int half = w & 1;               // even/odd segment owner
    const int row  = blockIdx.x * 2 + (w >> 1);
    const int n = L[row] + 1;             // valid atoms, 2..2047
    const int nIter = (n + 255) >> 8;     // segments of 256 atoms, 1..8
    const int cnt = (nIter > half) ? ((nIter - half + 1) >> 1) : 0;

    const float* gX = X + (size_t)row * ROWF + (size_t)lane * 12;
    const float* gY = Y + (size_t)row * ROWF + (size_t)lane * 12;

    float v[NACC];
#pragma unroll
    for (int k = 0; k < NACC; ++k) v[k] = 0.0f;

    float4 cx0, cx1, cx2, cy0, cy1, cy2;
    if (cnt > 0) {
        const float4* px = (const float4*)(gX + half * 768);
        const float4* py = (const float4*)(gY + half * 768);
        cx0 = px[0]; cx1 = px[1]; cx2 = px[2];
        cy0 = py[0]; cy1 = py[1]; cy2 = py[2];
    }

    for (int s = 0; s < cnt; ++s) {
        const int it = half + 2 * s;
        const bool more = (s + 1 < cnt);
        float4 nx0, nx1, nx2, ny0, ny1, ny2;
        if (more) {
            const float4* px = (const float4*)(gX + (it + 2) * 768);
            const float4* py = (const float4*)(gY + (it + 2) * 768);
            nx0 = px[0]; nx1 = px[1]; nx2 = px[2];
            ny0 = py[0]; ny1 = py[1]; ny2 = py[2];
        }

        float fx[12], fy[12];
        fx[0]=cx0.x; fx[1]=cx0.y; fx[2]=cx0.z; fx[3]=cx0.w;
        fx[4]=cx1.x; fx[5]=cx1.y; fx[6]=cx1.z; fx[7]=cx1.w;
        fx[8]=cx2.x; fx[9]=cx2.y; fx[10]=cx2.z; fx[11]=cx2.w;
        fy[0]=cy0.x; fy[1]=cy0.y; fy[2]=cy0.z; fy[3]=cy0.w;
        fy[4]=cy1.x; fy[5]=cy1.y; fy[6]=cy1.z; fy[7]=cy1.w;
        fy[8]=cy2.x; fy[9]=cy2.y; fy[10]=cy2.z; fy[11]=cy2.w;

        const int abase = it * 256 + lane * 4;
#pragma unroll
        for (int j = 0; j < 4; ++j) {
            const float msk = (abase + j < n) ? 1.0f : 0.0f;
            const float x0 = fx[3 * j + 0] * msk;
            const float x1 = fx[3 * j + 1] * msk;
            const float x2 = fx[3 * j + 2] * msk;
            const float y0 = fy[3 * j + 0] * msk;
            const float y1 = fy[3 * j + 1] * msk;
            const float y2 = fy[3 * j + 2] * msk;
            v[0] += x0; v[1] += x1; v[2] += x2;
            v[3] += y0; v[4] += y1; v[5] += y2;
            v[6] += x0 * x0 + x1 * x1 + x2 * x2;
            v[7] += y0 * y0 + y1 * y1 + y2 * y2;
            v[8]  += x0 * y0; v[9]  += x0 * y1; v[10] += x0 * y2;
            v[11] += x1 * y0; v[12] += x1 * y1; v[13] += x1 * y2;
            v[14] += x2 * y0; v[15] += x2 * y1; v[16] += x2 * y2;
        }

        if (more) {
            cx0 = nx0; cx1 = nx1; cx2 = nx2;
            cy0 = ny0; cy1 = ny1; cy2 = ny2;
        }
    }

    // wave-64 reduction
#pragma unroll
    for (int k = 0; k < NACC; ++k) {
        float t = v[k];
        t += __shfl_down(t, 32);
        t += __shfl_down(t, 16);
        t += __shfl_down(t, 8);
        t += __shfl_down(t, 4);
        t += __shfl_down(t, 2);
        t += __shfl_down(t, 1);
        v[k] = t;
    }

    __shared__ float red[4][NACC];
    if (lane == 0) {
#pragma unroll
        for (int k = 0; k < NACC; ++k) red[w][k] = v[k];
    }
    __syncthreads();

    // combine wave pairs: waves {0,1} -> rowA (blockIdx*2), {2,3} -> rowB
    if (w == 0 && lane < NACC) {
        WS[(size_t)lane * B + blockIdx.x * 2] = red[0][lane] + red[1][lane];
    }
    if (w == 2 && lane < NACC) {
        WS[(size_t)lane * B + blockIdx.x * 2 + 1] = red[2][lane] + red[3][lane];
    }
}

__global__ __launch_bounds__(256) void kabsch_eig_kernel(
    const float* __restrict__ WS,   // NACC x B
    const int* __restrict__ L,
    float* __restrict__ OUT,
    int B)
{
    const int row = blockIdx.x * 256 + threadIdx.x;
    if (row >= B) return;
    const int n = L[row] + 1;

    double s[NACC];
#pragma unroll
    for (int k = 0; k < NACC; ++k)
        s[k] = (double)WS[(size_t)k * B + row];

    const double inv_n = 1.0 / (double)n;
    const double sx0 = s[0], sx1 = s[1], sx2 = s[2];
    const double sy0 = s[3], sy1 = s[4], sy2 = s[5];
    const double ssq = s[6] + s[7]
        - (sx0 * sx0 + sx1 * sx1 + sx2 * sx2) * inv_n
        - (sy0 * sy0 + sy1 * sy1 + sy2 * sy2) * inv_n;

    double C[3][3];
    C[0][0] = s[8]  - sx0 * sy0 * inv_n;
    C[0][1] = s[9]  - sx0 * sy1 * inv_n;
    C[0][2] = s[10] - sx0 * sy2 * inv_n;
    C[1][0] = s[11] - sx1 * sy0 * inv_n;
    C[1][1] = s[12] - sx1 * sy1 * inv_n;
    C[1][2] = s[13] - sx1 * sy2 * inv_n;
    C[2][0] = s[14] - sx2 * sy0 * inv_n;
    C[2][1] = s[15] - sx2 * sy1 * inv_n;
    C[2][2] = s[16] - sx2 * sy2 * inv_n;

    const double det =
          C[0][0] * (C[1][1] * C[2][2] - C[1][2] * C[2][1])
        - C[0][1] * (C[1][0] * C[2][2] - C[1][2] * C[2][0])
        + C[0][2] * (C[1][0] * C[2][1] - C[1][1] * C[2][0]);

    double A[3][3];
#pragma unroll
    for (int i = 0; i < 3; ++i)
#pragma unroll
        for (int j = 0; j < 3; ++j)
            A[i][j] = C[0][i] * C[0][j] + C[1][i] * C[1][j] + C[2][i] * C[2][j];

    const double q  = (A[0][0] + A[1][1] + A[2][2]) / 3.0;
    const double p1 = A[0][1] * A[0][1] + A[0][2] * A[0][2] + A[1][2] * A[1][2];
    const double a00 = A[0][0] - q, a11 = A[1][1] - q, a22 = A[2][2] - q;
    const double p2 = a00 * a00 + a11 * a11 + a22 * a22 + 2.0 * p1;
    const double p  = sqrt(p2 / 6.0);

    double e1, e2, e3;
    if (p < 1e-30) {
        e1 = e2 = e3 = q;
    } else {
        const double ip = 1.0 / p;
        const double b00 = a00 * ip, b11 = a11 * ip, b22 = a22 * ip;
        const double b01 = A[0][1] * ip, b02 = A[0][2] * ip, b12 = A[1][2] * ip;
        double r = 0.5 * (b00 * (b11 * b22 - b12 * b12)
                        - b01 * (b01 * b22 - b12 * b02)
                        + b02 * (b01 * b12 - b11 * b02));
        r = fmin(1.0, fmax(-1.0, r));
        const double phi = acos(r) / 3.0;
        e1 = q + 2.0 * p * cos(phi);
        e3 = q + 2.0 * p * cos(phi + 2.0 * M_PI / 3.0);
        e2 = 3.0 * q - e1 - e3;
    }

    const double S0 = sqrt(fmax(e1, 0.0));
    const double S1 = sqrt(fmax(e2, 0.0));
    const double S2 = sqrt(fmax(e3, 0.0));
    const double d  = (det > 0.0) ? 1.0 : ((det < 0.0) ? -1.0 : 0.0);
    const double tr = S0 + S1 + d * S2;

    const double msd = fmax(ssq - 2.0 * tr, 0.0) * inv_n;
    OUT[row] = (float)sqrt(msd + 1e-12);
}

extern "C" void kernel_launch(void* const* d_in, const int* in_sizes, int n_in,
                              void* d_out, int out_size, void* d_ws, size_t ws_size,
                              hipStream_t stream) {
    const float* X = (const float*)d_in[0];
    const float* Y = (const float*)d_in[1];
    const int* L = (const int*)d_in[2];
    float* OUT = (float*)d_out;
    float* WS = (float*)d_ws;              // NACC * B floats

    const int B = in_sizes[2];             // 4096
    kabsch_moments_kernel<<<B / 2, 256, 0, stream>>>(X, Y, L, WS, B);
    kabsch_eig_kernel<<<(B + 255) / 256, 256, 0, stream>>>(WS, L, OUT, B);
}